// Round 2
// baseline (1434.590 us; speedup 1.0000x reference)
//
#include <hip/hip_runtime.h>

typedef unsigned long long u64;
typedef unsigned int u32;

#define V_ 1000000
#define STEPS_ 10
#define EPS_ 1e-5f
#define MARGIN_ 0.06f
#define FP8_SCALE 2048.0f
#define FP8_INV (1.0f / 2048.0f)
#define NCH 8192   // wave-chunks covering V (2048 blocks x 4 waves)
#define CH 123     // rows per chunk: 8192*123 >= 1e6
#define NBLK 64    // step_kernel grid (one FFN2 output dim per block)

// ---------------------------------------------------------------------------
// Packed (value, ~idx) so u64 max == argmax with lowest-index tie-break.
// ---------------------------------------------------------------------------
__device__ __forceinline__ u64 pack_best(float v, int idx) {
    u32 u = __float_as_uint(v);
    u = (u & 0x80000000u) ? ~u : (u | 0x80000000u);
    return ((u64)u << 32) | (u64)(~(u32)idx);
}
__device__ __forceinline__ int unpack_idx(u64 p) { return (int)(~(u32)p); }
__device__ __forceinline__ float unpack_val(u64 p) {
    u32 hi = (u32)(p >> 32);
    return __uint_as_float((hi & 0x80000000u) ? (hi ^ 0x80000000u) : ~hi);
}
__device__ __forceinline__ u64 shfl_xor_u64(u64 v, int m) {
    u32 lo = (u32)v, hi = (u32)(v >> 32);
    lo = (u32)__shfl_xor((int)lo, m);
    hi = (u32)__shfl_xor((int)hi, m);
    return ((u64)hi << 32) | lo;
}

// fp8(e4m3, OCP, HW cvt) 16-element dot: u = 16 packed fp8, q[16] pre-scaled.
// cvt_pk_f32_fp8 returns a 2-elem float vector -> index with [0]/[1].
#define FP8_DOT16(u, q, p) do { \
    auto a0 = __builtin_amdgcn_cvt_pk_f32_fp8((u).x, false); \
    auto a1 = __builtin_amdgcn_cvt_pk_f32_fp8((u).x, true);  \
    auto b0 = __builtin_amdgcn_cvt_pk_f32_fp8((u).y, false); \
    auto b1 = __builtin_amdgcn_cvt_pk_f32_fp8((u).y, true);  \
    auto c0 = __builtin_amdgcn_cvt_pk_f32_fp8((u).z, false); \
    auto c1 = __builtin_amdgcn_cvt_pk_f32_fp8((u).z, true);  \
    auto d0 = __builtin_amdgcn_cvt_pk_f32_fp8((u).w, false); \
    auto d1 = __builtin_amdgcn_cvt_pk_f32_fp8((u).w, true);  \
    p = q[0]*a0[0] + q[1]*a0[1] + q[2]*a1[0] + q[3]*a1[1] \
      + q[4]*b0[0] + q[5]*b0[1] + q[6]*b1[0] + q[7]*b1[1] \
      + q[8]*c0[0] + q[9]*c0[1] + q[10]*c1[0] + q[11]*c1[1] \
      + q[12]*d0[0] + q[13]*d0[1] + q[14]*d1[0] + q[15]*d1[1]; \
} while (0)

// ---------------------------------------------------------------------------
// Device-scope grid barrier among the NBLK co-resident blocks of one launch.
// Counter is single-use per (step, phase); zeroed by memset each launch.
// ---------------------------------------------------------------------------
__device__ __forceinline__ void grid_bar(u32* ctr, u32 expect) {
    __threadfence();
    __syncthreads();
    if (threadIdx.x == 0) {
        __hip_atomic_fetch_add(ctr, 1u, __ATOMIC_ACQ_REL, __HIP_MEMORY_SCOPE_AGENT);
        while (__hip_atomic_load(ctr, __ATOMIC_ACQUIRE, __HIP_MEMORY_SCOPE_AGENT) < expect)
            __builtin_amdgcn_s_sleep(2);
    }
    __syncthreads();
    __threadfence();
}

// ---------------------------------------------------------------------------
// Exact argmax resolve (blockDim=256). cand[NCH] holds per-chunk approx bests.
// Sound against same-chunk shadowing: every chunk whose best is within MARGIN
// of the global approx max is rescanned row-by-row in fp8; rows above the
// threshold are rescored in exact fp32.
// ---------------------------------------------------------------------------
__device__ int resolve_argmax(const u64* __restrict__ cand,
                              const u32* __restrict__ emb8,
                              const float* __restrict__ item_emb,
                              const float* __restrict__ y_last,
                              const float* __restrict__ lnw,
                              const float* __restrict__ lnb,
                              float* s_xl, int* s_list, int* s_qg, u64* s_wm,
                              int* s_cnt, int* s_qcnt, u64* s_best)
{
    const int tid = threadIdx.x;
    if (tid < 64) {
        float v = y_last[tid];
        float m = v;
        #pragma unroll
        for (int o = 1; o < 64; o <<= 1) m += __shfl_xor(m, o);
        m *= (1.f / 64.f);
        float df = v - m;
        float var = df * df;
        #pragma unroll
        for (int o = 1; o < 64; o <<= 1) var += __shfl_xor(var, o);
        var *= (1.f / 64.f);
        s_xl[tid] = df * (1.f / sqrtf(var + EPS_)) * lnw[tid] + lnb[tid];
    }
    if (tid == 0) { *s_cnt = 0; *s_qcnt = 0; *s_best = 0ull; }
    __syncthreads();

    // pass 1: global approx max over per-chunk bests
    u64 m = 0ull;
    for (int i = tid; i < NCH; i += 256) { u64 c = cand[i]; if (c > m) m = c; }
    #pragma unroll
    for (int o = 1; o < 64; o <<= 1) { u64 x = shfl_xor_u64(m, o); if (x > m) m = x; }
    if ((tid & 63) == 0) s_wm[tid >> 6] = m;
    __syncthreads();
    if (tid == 0) {
        u64 b = s_wm[0];
        for (int i = 1; i < 4; i++) if (s_wm[i] > b) b = s_wm[i];
        s_wm[0] = b;
    }
    __syncthreads();
    const float thr = unpack_val(s_wm[0]) - MARGIN_;

    // pass 2: collect qualifying chunks
    for (int i = tid; i < NCH; i += 256) {
        if (unpack_val(cand[i]) >= thr) {
            int p = atomicAdd(s_qcnt, 1);
            if (p < 64) s_qg[p] = i;
        }
    }
    __syncthreads();
    int nq = *s_qcnt; if (nq > 64) nq = 64;

    // phase B: fp8 rescan of qualifying chunks -> candidate rows
    {
        const int l4 = tid & 3, rl = tid >> 2;  // 64 rows per pass
        float q[16];
        #pragma unroll
        for (int i = 0; i < 16; i++) q[i] = s_xl[l4 * 16 + i] * FP8_INV;
        for (int ci = 0; ci < nq; ci++) {
            const int r0 = s_qg[ci] * CH;
            #pragma unroll
            for (int half = 0; half < 2; half++) {
                int loc = half * 64 + rl;
                int row = r0 + loc;
                if (loc < CH && row < V_) {
                    uint4 u = ((const uint4*)emb8)[(size_t)row * 4 + l4];
                    float p;
                    FP8_DOT16(u, q, p);
                    p += __shfl_xor(p, 1);
                    p += __shfl_xor(p, 2);
                    if (l4 == 0 && p >= thr - 1e-3f) {
                        int pp = atomicAdd(s_cnt, 1);
                        if (pp < 128) s_list[pp] = row;
                    }
                }
            }
        }
    }
    __syncthreads();
    int n = *s_cnt; if (n > 128) n = 128;

    // phase C: exact fp32 rescore
    const int wid = tid >> 6, lane = tid & 63;
    for (int c = wid; c < n; c += 4) {
        int row = s_list[c];
        float p = s_xl[lane] * item_emb[(size_t)row * 64 + lane];
        #pragma unroll
        for (int o = 1; o < 64; o <<= 1) p += __shfl_xor(p, o);
        if (lane == 0) atomicMax(s_best, pack_best(p, row));
    }
    __syncthreads();
    return unpack_idx(*s_best);
}

// ---------------------------------------------------------------------------
// Fused per-step transformer: resolve prev argmax, both encoder layers, ends
// with y_last[64]. 64 blocks x 256; 3 device-scope grid barriers.
// ---------------------------------------------------------------------------
__global__ __launch_bounds__(256) void step_kernel(
    const float* __restrict__ ht, const float* __restrict__ item_emb,
    const float* __restrict__ pos_emb,
    const float* __restrict__ ipw, const float* __restrict__ ipb,
    const float* __restrict__ ow, const float* __restrict__ ob,
    const float* __restrict__ l1w, const float* __restrict__ l1b,
    const float* __restrict__ l2w, const float* __restrict__ l2b,
    const float* __restrict__ f1w, const float* __restrict__ f1b,
    const float* __restrict__ f2w, const float* __restrict__ f2b,
    const u64* __restrict__ cand, const u32* __restrict__ emb8,
    float* __restrict__ y_last,
    int* __restrict__ gen_idx, float* __restrict__ gen_out,
    float* __restrict__ y0, float* __restrict__ hbuf, float* __restrict__ hbuf2,
    u32* __restrict__ bar, int t)
{
    const int S = t + 1;
    const int tid = threadIdx.x, bid = blockIdx.x;
    __shared__ __align__(16) float x[640], qkv[1920], o_[640], y2[640], xps[640];
    __shared__ __align__(16) float xpl[64];
    __shared__ float att[400], rm[10], rr[10], sw[4][10], xl[64], ol[64], y2l[64];
    __shared__ int list[128], qg[64], cnt, qcnt;
    __shared__ u64 wm[4], best;

    const float* ipw1 = ipw + 192 * 64;  const float* ipb1 = ipb + 192;
    const float* ow1  = ow + 64 * 64;    const float* ob1  = ob + 64;
    const float* l1w1 = l1w + 64;        const float* l1b1 = l1b + 64;
    const float* l2w1 = l2w + 64;        const float* l2b1 = l2b + 64;
    const float* f1w1 = f1w + 2048 * 64; const float* f1b1 = f1b + 2048;
    const float* f2w1 = f2w + (size_t)64 * 2048; const float* f2b1 = f2b + 64;

    int newidx = -1;
    if (t > 0) {
        newidx = resolve_argmax(cand, emb8, item_emb, y_last, l2w1, l2b1,
                                xl, list, qg, wm, &cnt, &qcnt, &best);
        if (bid == 0 && tid == 0) { gen_idx[t - 1] = newidx; gen_out[t - 1] = (float)newidx; }
    }
    __syncthreads();

    // build x (redundant per block)
    for (int i = tid; i < S * 64; i += 256) {
        int s = i >> 6, d = i & 63;
        float base;
        if (s == 0) base = ht[d];
        else {
            int gi = (s == t) ? newidx : gen_idx[s - 1];
            base = item_emb[(size_t)gi * 64 + d];
        }
        x[i] = base + pos_emb[i];
    }
    __syncthreads();

    // QKV layer 0
    for (int i = tid; i < S * 192; i += 256) {
        int s = i / 192, j2 = i % 192;
        float acc = ipb[j2];
        const float4* wr = (const float4*)(ipw + j2 * 64);
        const float4* xr = (const float4*)(x + s * 64);
        #pragma unroll
        for (int k = 0; k < 16; k++) {
            float4 w4 = wr[k], xv = xr[k];
            acc += w4.x * xv.x + w4.y * xv.y + w4.z * xv.z + w4.w * xv.w;
        }
        qkv[i] = acc;
    }
    __syncthreads();

    // attention layer 0 (all rows, redundant)
    for (int i = tid; i < 4 * S * S; i += 256) {
        int h = i / (S * S), r = i % (S * S);
        int si = r / S, ti = r % S;
        const float* qr = qkv + si * 192 + h * 16;
        const float* kr = qkv + ti * 192 + 64 + h * 16;
        float acc = 0.f;
        #pragma unroll
        for (int k = 0; k < 16; k++) acc += qr[k] * kr[k];
        att[(h * S + si) * S + ti] = acc * 0.25f;
    }
    __syncthreads();
    for (int i = tid; i < 4 * S; i += 256) {
        float* row = att + i * S;
        float mx = row[0];
        for (int j2 = 1; j2 < S; j2++) mx = fmaxf(mx, row[j2]);
        float sm = 0.f;
        for (int j2 = 0; j2 < S; j2++) { float e = expf(row[j2] - mx); row[j2] = e; sm += e; }
        float inv = 1.f / sm;
        for (int j2 = 0; j2 < S; j2++) row[j2] *= inv;
    }
    __syncthreads();
    for (int i = tid; i < S * 64; i += 256) {
        int si = i >> 6, d = i & 63, h = d >> 4, dh = d & 15;
        const float* ar = att + (h * S + si) * S;
        float acc = 0.f;
        for (int ti = 0; ti < S; ti++) acc += ar[ti] * qkv[ti * 192 + 128 + h * 16 + dh];
        o_[i] = acc;
    }
    __syncthreads();
    for (int i = tid; i < S * 64; i += 256) {
        int s = i >> 6, d = i & 63;
        float acc = ob[d] + x[i];
        const float4* wr = (const float4*)(ow + d * 64);
        const float4* orow = (const float4*)(o_ + s * 64);
        #pragma unroll
        for (int k = 0; k < 16; k++) {
            float4 w4 = wr[k], ov = orow[k];
            acc += w4.x * ov.x + w4.y * ov.y + w4.z * ov.z + w4.w * ov.w;
        }
        y2[i] = acc;
    }
    __syncthreads();
    if (tid < S) {
        const float* yr = y2 + tid * 64;
        float m = 0.f;
        for (int k = 0; k < 64; k++) m += yr[k];
        m *= (1.f / 64.f);
        float v = 0.f;
        for (int k = 0; k < 64; k++) { float df = yr[k] - m; v += df * df; }
        rm[tid] = m;
        rr[tid] = 1.f / sqrtf(v * (1.f / 64.f) + EPS_);
    }
    __syncthreads();
    for (int i = tid; i < S * 64; i += 256) {
        int s = i >> 6, d = i & 63;
        xps[i] = (y2[i] - rm[s]) * rr[s] * l1w[d] + l1b[d];
    }
    __syncthreads();

    // FFN1 layer 0: 32 hidden units per block, all S rows
    const int jl = tid >> 3, kp = tid & 7;
    const int j = bid * 32 + jl;
    {
        const float4* wr = (const float4*)(f1w + (size_t)j * 64);
        float4 wa = wr[kp * 2], wb = wr[kp * 2 + 1];
        float b1 = f1b[j];
        for (int s = 0; s < S; s++) {
            const float4* xr = (const float4*)(xps + s * 64);
            float4 xa = xr[kp * 2], xb = xr[kp * 2 + 1];
            float p = wa.x * xa.x + wa.y * xa.y + wa.z * xa.z + wa.w * xa.w
                    + wb.x * xb.x + wb.y * xb.y + wb.z * xb.z + wb.w * xb.w;
            p += __shfl_xor(p, 1);
            p += __shfl_xor(p, 2);
            p += __shfl_xor(p, 4);
            if (kp == 0) hbuf[s * 2048 + j] = fmaxf(p + b1, 0.f);
        }
    }
    grid_bar(bar + t * 4 + 0, NBLK);

    // FFN2 layer 0: one output dim per block
    {
        const int d = bid;
        const float4* w4 = (const float4*)(f2w + (size_t)d * 2048 + tid * 8);
        float4 w0 = w4[0], w1 = w4[1];
        for (int s = 0; s < S; s++) {
            const float4* h4 = (const float4*)(hbuf + s * 2048 + tid * 8);
            float4 h0 = h4[0], h1 = h4[1];
            float p = w0.x * h0.x + w0.y * h0.y + w0.z * h0.z + w0.w * h0.w
                    + w1.x * h1.x + w1.y * h1.y + w1.z * h1.z + w1.w * h1.w;
            #pragma unroll
            for (int o = 1; o < 64; o <<= 1) p += __shfl_xor(p, o);
            if ((tid & 63) == 0) sw[tid >> 6][s] = p;
        }
        __syncthreads();
        if (tid < S)
            y0[tid * 64 + d] = sw[0][tid] + sw[1][tid] + sw[2][tid] + sw[3][tid]
                             + f2b[d] + xps[tid * 64 + d];
    }
    grid_bar(bar + t * 4 + 1, NBLK);

    // LN2(y0) -> x (reused as layer-1 input), redundant per block
    for (int i = tid; i < S * 64; i += 256) y2[i] = y0[i];
    __syncthreads();
    if (tid < S) {
        const float* yr = y2 + tid * 64;
        float m = 0.f;
        for (int k = 0; k < 64; k++) m += yr[k];
        m *= (1.f / 64.f);
        float v = 0.f;
        for (int k = 0; k < 64; k++) { float df = yr[k] - m; v += df * df; }
        rm[tid] = m;
        rr[tid] = 1.f / sqrtf(v * (1.f / 64.f) + EPS_);
    }
    __syncthreads();
    for (int i = tid; i < S * 64; i += 256) {
        int s = i >> 6, d = i & 63;
        x[i] = (y2[i] - rm[s]) * rr[s] * l2w[d] + l2b[d];
    }
    __syncthreads();

    // QKV layer 1
    for (int i = tid; i < S * 192; i += 256) {
        int s = i / 192, j2 = i % 192;
        float acc = ipb1[j2];
        const float4* wr = (const float4*)(ipw1 + j2 * 64);
        const float4* xr = (const float4*)(x + s * 64);
        #pragma unroll
        for (int k = 0; k < 16; k++) {
            float4 w4 = wr[k], xv = xr[k];
            acc += w4.x * xv.x + w4.y * xv.y + w4.z * xv.z + w4.w * xv.w;
        }
        qkv[i] = acc;
    }
    __syncthreads();

    // attention layer 1: last query row only
    for (int i = tid; i < 4 * S; i += 256) {
        int h = i / S, ti = i % S;
        const float* qr = qkv + (S - 1) * 192 + h * 16;
        const float* kr = qkv + ti * 192 + 64 + h * 16;
        float acc = 0.f;
        #pragma unroll
        for (int k = 0; k < 16; k++) acc += qr[k] * kr[k];
        att[h * S + ti] = acc * 0.25f;
    }
    __syncthreads();
    if (tid < 4) {
        float* row = att + tid * S;
        float mx = row[0];
        for (int j2 = 1; j2 < S; j2++) mx = fmaxf(mx, row[j2]);
        float sm = 0.f;
        for (int j2 = 0; j2 < S; j2++) { float e = expf(row[j2] - mx); row[j2] = e; sm += e; }
        float inv = 1.f / sm;
        for (int j2 = 0; j2 < S; j2++) row[j2] *= inv;
    }
    __syncthreads();
    if (tid < 64) {
        int h = tid >> 4, dh = tid & 15;
        const float* ar = att + h * S;
        float acc = 0.f;
        for (int ti = 0; ti < S; ti++) acc += ar[ti] * qkv[ti * 192 + 128 + h * 16 + dh];
        ol[tid] = acc;
    }
    __syncthreads();
    if (tid < 64) {
        float acc = ob1[tid] + x[(S - 1) * 64 + tid];
        const float* wr = ow1 + tid * 64;
        for (int k = 0; k < 64; k++) acc += ol[k] * wr[k];
        y2l[tid] = acc;
    }
    __syncthreads();
    if (tid < 64) {
        float v = y2l[tid];
        float m = v;
        #pragma unroll
        for (int o = 1; o < 64; o <<= 1) m += __shfl_xor(m, o);
        m *= (1.f / 64.f);
        float df = v - m;
        float var = df * df;
        #pragma unroll
        for (int o = 1; o < 64; o <<= 1) var += __shfl_xor(var, o);
        float r = 1.f / sqrtf(var * (1.f / 64.f) + EPS_);
        xpl[tid] = df * r * l1w1[tid] + l1b1[tid];
    }
    __syncthreads();

    // FFN1 layer 1 (last row only)
    {
        const float4* wr = (const float4*)(f1w1 + (size_t)j * 64);
        float4 wa = wr[kp * 2], wb = wr[kp * 2 + 1];
        const float4* xr = (const float4*)xpl;
        float4 xa = xr[kp * 2], xb = xr[kp * 2 + 1];
        float p = wa.x * xa.x + wa.y * xa.y + wa.z * xa.z + wa.w * xa.w
                + wb.x * xb.x + wb.y * xb.y + wb.z * xb.z + wb.w * xb.w;
        p += __shfl_xor(p, 1);
        p += __shfl_xor(p, 2);
        p += __shfl_xor(p, 4);
        if (kp == 0) hbuf2[j] = fmaxf(p + f1b1[j], 0.f);
    }
    grid_bar(bar + t * 4 + 2, NBLK);

    // FFN2 layer 1 (last row) -> y_last
    {
        const int d = bid;
        const float4* w4 = (const float4*)(f2w1 + (size_t)d * 2048 + tid * 8);
        const float4* h4 = (const float4*)(hbuf2 + tid * 8);
        float4 w0 = w4[0], w1 = w4[1], h0 = h4[0], h1 = h4[1];
        float p = w0.x * h0.x + w0.y * h0.y + w0.z * h0.z + w0.w * h0.w
                + w1.x * h1.x + w1.y * h1.y + w1.z * h1.z + w1.w * h1.w;
        #pragma unroll
        for (int o = 1; o < 64; o <<= 1) p += __shfl_xor(p, o);
        if ((tid & 63) == 0) sw[tid >> 6][0] = p;
        __syncthreads();
        if (tid == 0) y_last[d] = sw[0][0] + sw[1][0] + sw[2][0] + sw[3][0] + f2b1[d] + xpl[d];
    }
}

// ---------------------------------------------------------------------------
// Step-0 scan: exact fp32 argmax approx + fused fp8 quantization of item_emb.
// Per-WAVE contiguous chunks of CH rows; cand[g] = chunk best. 2048 blocks.
// ---------------------------------------------------------------------------
__global__ __launch_bounds__(256) void scan0_kernel(
    const float* __restrict__ item_emb, const float* __restrict__ y_last,
    const float* __restrict__ lnw, const float* __restrict__ lnb,
    u64* __restrict__ cand, float* __restrict__ xl_all, u32* __restrict__ emb8)
{
    const int tid = threadIdx.x;
    __shared__ float xl[64];
    if (tid < 64) {
        float v = y_last[tid];
        float m = v;
        #pragma unroll
        for (int o = 1; o < 64; o <<= 1) m += __shfl_xor(m, o);
        m *= (1.f / 64.f);
        float df = v - m;
        float var = df * df;
        #pragma unroll
        for (int o = 1; o < 64; o <<= 1) var += __shfl_xor(var, o);
        float r = 1.f / sqrtf(var * (1.f / 64.f) + EPS_);
        float v_ = df * r * lnw[tid] + lnb[tid];
        xl[tid] = v_;
        if (blockIdx.x == 0) xl_all[tid] = v_;
    }
    __syncthreads();

    const int lane = tid & 63, wid = tid >> 6;
    const int g = blockIdx.x * 4 + wid;
    const int l16 = lane & 15, rl = lane >> 4;   // 4 rows per iter
    float4 q = ((const float4*)xl)[l16];
    const int r0 = g * CH;
    u64 lb = 0ull;
    for (int it = 0; it < 31; it++) {
        int loc = it * 4 + rl;
        int row = r0 + loc;
        if (loc < CH && row < V_) {
            float4 e = ((const float4*)(item_emb + (size_t)row * 64))[l16];
            u32 pk8 = (u32)__builtin_amdgcn_cvt_pk_fp8_f32(e.x * FP8_SCALE, e.y * FP8_SCALE, 0, false);
            pk8 = (u32)__builtin_amdgcn_cvt_pk_fp8_f32(e.z * FP8_SCALE, e.w * FP8_SCALE, (int)pk8, true);
            emb8[(size_t)row * 16 + l16] = pk8;
            float p = q.x * e.x + q.y * e.y + q.z * e.z + q.w * e.w;
            p += __shfl_xor(p, 1);
            p += __shfl_xor(p, 2);
            p += __shfl_xor(p, 4);
            p += __shfl_xor(p, 8);
            if (l16 == 0) { u64 pk = pack_best(p, row); if (pk > lb) lb = pk; }
        }
    }
    #pragma unroll
    for (int o = 1; o < 64; o <<= 1) { u64 xv = shfl_xor_u64(lb, o); if (xv > lb) lb = xv; }
    if (lane == 0) cand[g] = lb;
}

// ---------------------------------------------------------------------------
// Steps 1..9 argmax scan over the fp8 copy (64 MB). Same chunk mapping.
// ---------------------------------------------------------------------------
__global__ __launch_bounds__(256) void scan_fp8_kernel(
    const u32* __restrict__ emb8, const float* __restrict__ y_last,
    const float* __restrict__ lnw, const float* __restrict__ lnb,
    u64* __restrict__ cand, float* __restrict__ xl_all, int t)
{
    const int tid = threadIdx.x;
    __shared__ float xls[64];
    if (tid < 64) {
        float v = y_last[tid];
        float m = v;
        #pragma unroll
        for (int o = 1; o < 64; o <<= 1) m += __shfl_xor(m, o);
        m *= (1.f / 64.f);
        float df = v - m;
        float var = df * df;
        #pragma unroll
        for (int o = 1; o < 64; o <<= 1) var += __shfl_xor(var, o);
        float r = 1.f / sqrtf(var * (1.f / 64.f) + EPS_);
        float v_ = df * r * lnw[tid] + lnb[tid];
        if (blockIdx.x == 0) xl_all[t * 64 + tid] = v_;
        xls[tid] = v_ * FP8_INV;
    }
    __syncthreads();

    const int lane = tid & 63, wid = tid >> 6;
    const int g = blockIdx.x * 4 + wid;
    const int l4 = lane & 3, rl = lane >> 2;     // 16 rows per iter
    float q[16];
    #pragma unroll
    for (int i = 0; i < 16; i++) q[i] = xls[l4 * 16 + i];
    const int r0 = g * CH;
    u64 lb = 0ull;
    for (int it = 0; it < 8; it++) {
        int loc = it * 16 + rl;
        int row = r0 + loc;
        if (loc < CH && row < V_) {
            uint4 u = ((const uint4*)emb8)[(size_t)row * 4 + l4];
            float p;
            FP8_DOT16(u, q, p);
            p += __shfl_xor(p, 1);
            p += __shfl_xor(p, 2);
            if (l4 == 0) { u64 pk = pack_best(p, row); if (pk > lb) lb = pk; }
        }
    }
    #pragma unroll
    for (int o = 1; o < 64; o <<= 1) { u64 xv = shfl_xor_u64(lb, o); if (xv > lb) lb = xv; }
    if (lane == 0) cand[g] = lb;
}

// ---------------------------------------------------------------------------
// Final argmax resolve (step 9's token).
// ---------------------------------------------------------------------------
__global__ __launch_bounds__(256) void finalize_kernel(
    const u64* __restrict__ cand, const u32* __restrict__ emb8,
    const float* __restrict__ item_emb, const float* __restrict__ y_last,
    const float* __restrict__ lnw, const float* __restrict__ lnb,
    float* __restrict__ gen_out)
{
    __shared__ float xl[64];
    __shared__ int list[128], qg[64], cnt, qcnt;
    __shared__ u64 wm[4], best;
    int r = resolve_argmax(cand, emb8, item_emb, y_last, lnw, lnb,
                           xl, list, qg, wm, &cnt, &qcnt, &best);
    if (threadIdx.x == 0) gen_out[STEPS_ - 1] = (float)r;
}

// ---------------------------------------------------------------------------
// Batched exact logits: one fp32 pass over item_emb computes all 10 planes.
// 64-row tiles; LDS-staged so each plane is written in 256 B contiguous runs.
// ---------------------------------------------------------------------------
__global__ __launch_bounds__(256) void logits_all_kernel(
    const float* __restrict__ item_emb, const float* __restrict__ xl_all,
    float* __restrict__ out)
{
    const int tid = threadIdx.x;
    __shared__ __align__(16) float qs[640];
    __shared__ float acc[640];
    for (int i = tid; i < 640; i += 256) qs[i] = xl_all[i];
    __syncthreads();
    const int l16 = tid & 15, rl = tid >> 4;
    float4 qv[10];
    #pragma unroll
    for (int t2 = 0; t2 < 10; t2++) qv[t2] = ((const float4*)(qs + t2 * 64))[l16];
    for (int tile = blockIdx.x; tile < V_ / 64; tile += gridDim.x) {
        const int base = tile * 64;
        #pragma unroll
        for (int sub = 0; sub < 4; sub++) {
            const int r = sub * 16 + rl;
            float4 e = ((const float4*)(item_emb + (size_t)(base + r) * 64))[l16];
            #pragma unroll
            for (int t2 = 0; t2 < 10; t2++) {
                float p = qv[t2].x * e.x + qv[t2].y * e.y + qv[t2].z * e.z + qv[t2].w * e.w;
                p += __shfl_xor(p, 1);
                p += __shfl_xor(p, 2);
                p += __shfl_xor(p, 4);
                p += __shfl_xor(p, 8);
                if (l16 == 0) acc[r * 10 + t2] = p;
            }
        }
        __syncthreads();
        for (int i = tid; i < 640; i += 256) {
            int t2 = i >> 6, r = i & 63;
            out[(size_t)t2 * V_ + base + r] = acc[r * 10 + t2];
        }
        __syncthreads();
    }
}

extern "C" void kernel_launch(void* const* d_in, const int* in_sizes, int n_in,
                              void* d_out, int out_size, void* d_ws, size_t ws_size,
                              hipStream_t stream) {
    const float* ht       = (const float*)d_in[0];
    const float* item_emb = (const float*)d_in[1];
    const float* pos_emb  = (const float*)d_in[2];
    const float* ipw      = (const float*)d_in[3];
    const float* ipb      = (const float*)d_in[4];
    const float* ow       = (const float*)d_in[5];
    const float* ob       = (const float*)d_in[6];
    const float* l1w      = (const float*)d_in[7];
    const float* l1b      = (const float*)d_in[8];
    const float* l2w      = (const float*)d_in[9];
    const float* l2b      = (const float*)d_in[10];
    const float* f1w      = (const float*)d_in[11];
    const float* f1b      = (const float*)d_in[12];
    const float* f2w      = (const float*)d_in[13];
    const float* f2b      = (const float*)d_in[14];

    float* out = (float*)d_out;
    char* ws = (char*)d_ws;
    int*   gen_idx = (int*)ws;                 // [0,64)
    float* y_last  = (float*)(ws + 64);        // 64 floats
    float* y0      = (float*)(ws + 512);       // 10x64
    float* hbuf2   = (float*)(ws + 3072);      // 2048
    float* xl_all  = (float*)(ws + 11264);     // 10x64
    u32*   bar     = (u32*)(ws + 14336);       // 64 counters
    float* hbuf    = (float*)(ws + 16384);     // 10x2048
    u64*   cand    = (u64*)(ws + 131072);      // 8192 x u64
    u32*   emb8    = (u32*)(ws + 262144);      // 64 MB fp8 copy
    float* gen_out = out + (size_t)STEPS_ * V_;

    hipMemsetAsync(bar, 0, 256, stream);       // single-use barrier counters

    for (int t = 0; t < STEPS_; t++) {
        step_kernel<<<NBLK, 256, 0, stream>>>(
            ht, item_emb, pos_emb, ipw, ipb, ow, ob, l1w, l1b, l2w, l2b,
            f1w, f1b, f2w, f2b, cand, emb8, y_last, gen_idx, gen_out,
            y0, hbuf, hbuf2, bar, t);
        if (t == 0)
            scan0_kernel<<<2048, 256, 0, stream>>>(
                item_emb, y_last, l2w + 64, l2b + 64, cand, xl_all, emb8);
        else
            scan_fp8_kernel<<<2048, 256, 0, stream>>>(
                emb8, y_last, l2w + 64, l2b + 64, cand, xl_all, t);
    }
    finalize_kernel<<<1, 256, 0, stream>>>(
        cand, emb8, item_emb, y_last, l2w + 64, l2b + 64, gen_out);
    logits_all_kernel<<<2048, 256, 0, stream>>>(item_emb, xl_all, out);
}

// Round 3
// 1176.700 us; speedup vs baseline: 1.2192x; 1.2192x over previous
//
#include <hip/hip_runtime.h>

typedef unsigned long long u64;
typedef unsigned int u32;

#define V_ 1000000
#define STEPS_ 10
#define EPS_ 1e-5f
#define MARGIN_ 0.06f
#define FP8_SCALE 2048.0f
#define FP8_INV (1.0f / 2048.0f)
#define NCH 8192   // wave-chunks covering V (2048 blocks x 4 waves)
#define CH 123     // rows per chunk: 8192*123 >= 1e6
#define NBLK 64    // step_kernel grid (one FFN2 output dim per block)

// ---------------------------------------------------------------------------
// Packed (value, ~idx) so u64 max == argmax with lowest-index tie-break.
// ---------------------------------------------------------------------------
__device__ __forceinline__ u64 pack_best(float v, int idx) {
    u32 u = __float_as_uint(v);
    u = (u & 0x80000000u) ? ~u : (u | 0x80000000u);
    return ((u64)u << 32) | (u64)(~(u32)idx);
}
__device__ __forceinline__ int unpack_idx(u64 p) { return (int)(~(u32)p); }
__device__ __forceinline__ float unpack_val(u64 p) {
    u32 hi = (u32)(p >> 32);
    return __uint_as_float((hi & 0x80000000u) ? (hi ^ 0x80000000u) : ~hi);
}
__device__ __forceinline__ u64 shfl_xor_u64(u64 v, int m) {
    u32 lo = (u32)v, hi = (u32)(v >> 32);
    lo = (u32)__shfl_xor((int)lo, m);
    hi = (u32)__shfl_xor((int)hi, m);
    return ((u64)hi << 32) | lo;
}

// fp8(e4m3, OCP, HW cvt) 16-element dot: u = 16 packed fp8, q[16] pre-scaled.
// cvt_pk_f32_fp8 returns a 2-elem float vector -> index with [0]/[1].
#define FP8_DOT16(u, q, p) do { \
    auto a0 = __builtin_amdgcn_cvt_pk_f32_fp8((u).x, false); \
    auto a1 = __builtin_amdgcn_cvt_pk_f32_fp8((u).x, true);  \
    auto b0 = __builtin_amdgcn_cvt_pk_f32_fp8((u).y, false); \
    auto b1 = __builtin_amdgcn_cvt_pk_f32_fp8((u).y, true);  \
    auto c0 = __builtin_amdgcn_cvt_pk_f32_fp8((u).z, false); \
    auto c1 = __builtin_amdgcn_cvt_pk_f32_fp8((u).z, true);  \
    auto d0 = __builtin_amdgcn_cvt_pk_f32_fp8((u).w, false); \
    auto d1 = __builtin_amdgcn_cvt_pk_f32_fp8((u).w, true);  \
    p = q[0]*a0[0] + q[1]*a0[1] + q[2]*a1[0] + q[3]*a1[1] \
      + q[4]*b0[0] + q[5]*b0[1] + q[6]*b1[0] + q[7]*b1[1] \
      + q[8]*c0[0] + q[9]*c0[1] + q[10]*c1[0] + q[11]*c1[1] \
      + q[12]*d0[0] + q[13]*d0[1] + q[14]*d1[0] + q[15]*d1[1]; \
} while (0)

// ---------------------------------------------------------------------------
// Device-scope grid barrier among the NBLK co-resident blocks of one launch.
// Counter is single-use per (step, phase); zeroed by memset each launch.
// Release-RMW once; RELAXED polling (no per-poll cache maintenance); ONE
// acquire fence after the spin. CDNA L1 is write-through, so all block
// stores are in XCD-L2 by __syncthreads; the release wbl2 makes them
// agent-visible; consumer acquire inv drops stale L1/L2 lines.
// ---------------------------------------------------------------------------
__device__ __forceinline__ void grid_bar(u32* ctr, u32 expect) {
    __syncthreads();
    if (threadIdx.x == 0) {
        __hip_atomic_fetch_add(ctr, 1u, __ATOMIC_RELEASE, __HIP_MEMORY_SCOPE_AGENT);
        while (__hip_atomic_load(ctr, __ATOMIC_RELAXED, __HIP_MEMORY_SCOPE_AGENT) < expect)
            __builtin_amdgcn_s_sleep(4);
        __builtin_amdgcn_fence(__ATOMIC_ACQUIRE, "agent");
    }
    __syncthreads();
}

// ---------------------------------------------------------------------------
// Exact argmax resolve (blockDim=256). cand[NCH] holds per-chunk approx bests.
// Sound against same-chunk shadowing: every chunk whose best is within MARGIN
// of the global approx max is rescanned row-by-row in fp8; rows above the
// threshold are rescored in exact fp32.
// ---------------------------------------------------------------------------
__device__ int resolve_argmax(const u64* __restrict__ cand,
                              const u32* __restrict__ emb8,
                              const float* __restrict__ item_emb,
                              const float* __restrict__ y_last,
                              const float* __restrict__ lnw,
                              const float* __restrict__ lnb,
                              float* s_xl, int* s_list, int* s_qg, u64* s_wm,
                              int* s_cnt, int* s_qcnt, u64* s_best)
{
    const int tid = threadIdx.x;
    if (tid < 64) {
        float v = y_last[tid];
        float m = v;
        #pragma unroll
        for (int o = 1; o < 64; o <<= 1) m += __shfl_xor(m, o);
        m *= (1.f / 64.f);
        float df = v - m;
        float var = df * df;
        #pragma unroll
        for (int o = 1; o < 64; o <<= 1) var += __shfl_xor(var, o);
        var *= (1.f / 64.f);
        s_xl[tid] = df * (1.f / sqrtf(var + EPS_)) * lnw[tid] + lnb[tid];
    }
    if (tid == 0) { *s_cnt = 0; *s_qcnt = 0; *s_best = 0ull; }
    __syncthreads();

    // pass 1: global approx max over per-chunk bests
    u64 m = 0ull;
    for (int i = tid; i < NCH; i += 256) { u64 c = cand[i]; if (c > m) m = c; }
    #pragma unroll
    for (int o = 1; o < 64; o <<= 1) { u64 x = shfl_xor_u64(m, o); if (x > m) m = x; }
    if ((tid & 63) == 0) s_wm[tid >> 6] = m;
    __syncthreads();
    if (tid == 0) {
        u64 b = s_wm[0];
        for (int i = 1; i < 4; i++) if (s_wm[i] > b) b = s_wm[i];
        s_wm[0] = b;
    }
    __syncthreads();
    const float thr = unpack_val(s_wm[0]) - MARGIN_;

    // pass 2: collect qualifying chunks
    for (int i = tid; i < NCH; i += 256) {
        if (unpack_val(cand[i]) >= thr) {
            int p = atomicAdd(s_qcnt, 1);
            if (p < 64) s_qg[p] = i;
        }
    }
    __syncthreads();
    int nq = *s_qcnt; if (nq > 64) nq = 64;

    // phase B: fp8 rescan of qualifying chunks -> candidate rows
    {
        const int l4 = tid & 3, rl = tid >> 2;  // 64 rows per pass
        float q[16];
        #pragma unroll
        for (int i = 0; i < 16; i++) q[i] = s_xl[l4 * 16 + i] * FP8_INV;
        for (int ci = 0; ci < nq; ci++) {
            const int r0 = s_qg[ci] * CH;
            #pragma unroll
            for (int half = 0; half < 2; half++) {
                int loc = half * 64 + rl;
                int row = r0 + loc;
                if (loc < CH && row < V_) {
                    uint4 u = ((const uint4*)emb8)[(size_t)row * 4 + l4];
                    float p;
                    FP8_DOT16(u, q, p);
                    p += __shfl_xor(p, 1);
                    p += __shfl_xor(p, 2);
                    if (l4 == 0 && p >= thr - 1e-3f) {
                        int pp = atomicAdd(s_cnt, 1);
                        if (pp < 128) s_list[pp] = row;
                    }
                }
            }
        }
    }
    __syncthreads();
    int n = *s_cnt; if (n > 128) n = 128;

    // phase C: exact fp32 rescore
    const int wid = tid >> 6, lane = tid & 63;
    for (int c = wid; c < n; c += 4) {
        int row = s_list[c];
        float p = s_xl[lane] * item_emb[(size_t)row * 64 + lane];
        #pragma unroll
        for (int o = 1; o < 64; o <<= 1) p += __shfl_xor(p, o);
        if (lane == 0) atomicMax(s_best, pack_best(p, row));
    }
    __syncthreads();
    return unpack_idx(*s_best);
}

// ---------------------------------------------------------------------------
// Fused per-step transformer: resolve prev argmax, both encoder layers, ends
// with y_last[64]. 64 blocks x 256; 3 device-scope grid barriers.
// ---------------------------------------------------------------------------
__global__ __launch_bounds__(256) void step_kernel(
    const float* __restrict__ ht, const float* __restrict__ item_emb,
    const float* __restrict__ pos_emb,
    const float* __restrict__ ipw, const float* __restrict__ ipb,
    const float* __restrict__ ow, const float* __restrict__ ob,
    const float* __restrict__ l1w, const float* __restrict__ l1b,
    const float* __restrict__ l2w, const float* __restrict__ l2b,
    const float* __restrict__ f1w, const float* __restrict__ f1b,
    const float* __restrict__ f2w, const float* __restrict__ f2b,
    const u64* __restrict__ cand, const u32* __restrict__ emb8,
    float* __restrict__ y_last,
    int* __restrict__ gen_idx, float* __restrict__ gen_out,
    float* __restrict__ y0, float* __restrict__ hbuf, float* __restrict__ hbuf2,
    u32* __restrict__ bar, int t)
{
    const int S = t + 1;
    const int tid = threadIdx.x, bid = blockIdx.x;
    __shared__ __align__(16) float x[640], qkv[1920], o_[640], y2[640], xps[640];
    __shared__ __align__(16) float xpl[64];
    __shared__ float att[400], rm[10], rr[10], sw[4][10], xl[64], ol[64], y2l[64];
    __shared__ int list[128], qg[64], cnt, qcnt;
    __shared__ u64 wm[4], best;

    const float* ipw1 = ipw + 192 * 64;  const float* ipb1 = ipb + 192;
    const float* ow1  = ow + 64 * 64;    const float* ob1  = ob + 64;
    const float* l1w1 = l1w + 64;        const float* l1b1 = l1b + 64;
    const float* l2w1 = l2w + 64;        const float* l2b1 = l2b + 64;
    const float* f1w1 = f1w + 2048 * 64; const float* f1b1 = f1b + 2048;
    const float* f2w1 = f2w + (size_t)64 * 2048; const float* f2b1 = f2b + 64;

    int newidx = -1;
    if (t > 0) {
        newidx = resolve_argmax(cand, emb8, item_emb, y_last, l2w1, l2b1,
                                xl, list, qg, wm, &cnt, &qcnt, &best);
        if (bid == 0 && tid == 0) { gen_idx[t - 1] = newidx; gen_out[t - 1] = (float)newidx; }
    }
    __syncthreads();

    // build x (redundant per block)
    for (int i = tid; i < S * 64; i += 256) {
        int s = i >> 6, d = i & 63;
        float base;
        if (s == 0) base = ht[d];
        else {
            int gi = (s == t) ? newidx : gen_idx[s - 1];
            base = item_emb[(size_t)gi * 64 + d];
        }
        x[i] = base + pos_emb[i];
    }
    __syncthreads();

    // QKV layer 0
    for (int i = tid; i < S * 192; i += 256) {
        int s = i / 192, j2 = i % 192;
        float acc = ipb[j2];
        const float4* wr = (const float4*)(ipw + j2 * 64);
        const float4* xr = (const float4*)(x + s * 64);
        #pragma unroll
        for (int k = 0; k < 16; k++) {
            float4 w4 = wr[k], xv = xr[k];
            acc += w4.x * xv.x + w4.y * xv.y + w4.z * xv.z + w4.w * xv.w;
        }
        qkv[i] = acc;
    }
    __syncthreads();

    // attention layer 0 (all rows, redundant)
    for (int i = tid; i < 4 * S * S; i += 256) {
        int h = i / (S * S), r = i % (S * S);
        int si = r / S, ti = r % S;
        const float* qr = qkv + si * 192 + h * 16;
        const float* kr = qkv + ti * 192 + 64 + h * 16;
        float acc = 0.f;
        #pragma unroll
        for (int k = 0; k < 16; k++) acc += qr[k] * kr[k];
        att[(h * S + si) * S + ti] = acc * 0.25f;
    }
    __syncthreads();
    for (int i = tid; i < 4 * S; i += 256) {
        float* row = att + i * S;
        float mx = row[0];
        for (int j2 = 1; j2 < S; j2++) mx = fmaxf(mx, row[j2]);
        float sm = 0.f;
        for (int j2 = 0; j2 < S; j2++) { float e = expf(row[j2] - mx); row[j2] = e; sm += e; }
        float inv = 1.f / sm;
        for (int j2 = 0; j2 < S; j2++) row[j2] *= inv;
    }
    __syncthreads();
    for (int i = tid; i < S * 64; i += 256) {
        int si = i >> 6, d = i & 63, h = d >> 4, dh = d & 15;
        const float* ar = att + (h * S + si) * S;
        float acc = 0.f;
        for (int ti = 0; ti < S; ti++) acc += ar[ti] * qkv[ti * 192 + 128 + h * 16 + dh];
        o_[i] = acc;
    }
    __syncthreads();
    for (int i = tid; i < S * 64; i += 256) {
        int s = i >> 6, d = i & 63;
        float acc = ob[d] + x[i];
        const float4* wr = (const float4*)(ow + d * 64);
        const float4* orow = (const float4*)(o_ + s * 64);
        #pragma unroll
        for (int k = 0; k < 16; k++) {
            float4 w4 = wr[k], ov = orow[k];
            acc += w4.x * ov.x + w4.y * ov.y + w4.z * ov.z + w4.w * ov.w;
        }
        y2[i] = acc;
    }
    __syncthreads();
    if (tid < S) {
        const float* yr = y2 + tid * 64;
        float m = 0.f;
        for (int k = 0; k < 64; k++) m += yr[k];
        m *= (1.f / 64.f);
        float v = 0.f;
        for (int k = 0; k < 64; k++) { float df = yr[k] - m; v += df * df; }
        rm[tid] = m;
        rr[tid] = 1.f / sqrtf(v * (1.f / 64.f) + EPS_);
    }
    __syncthreads();
    for (int i = tid; i < S * 64; i += 256) {
        int s = i >> 6, d = i & 63;
        xps[i] = (y2[i] - rm[s]) * rr[s] * l1w[d] + l1b[d];
    }
    __syncthreads();

    // FFN1 layer 0: 32 hidden units per block, all S rows
    const int jl = tid >> 3, kp = tid & 7;
    const int j = bid * 32 + jl;
    {
        const float4* wr = (const float4*)(f1w + (size_t)j * 64);
        float4 wa = wr[kp * 2], wb = wr[kp * 2 + 1];
        float b1 = f1b[j];
        for (int s = 0; s < S; s++) {
            const float4* xr = (const float4*)(xps + s * 64);
            float4 xa = xr[kp * 2], xb = xr[kp * 2 + 1];
            float p = wa.x * xa.x + wa.y * xa.y + wa.z * xa.z + wa.w * xa.w
                    + wb.x * xb.x + wb.y * xb.y + wb.z * xb.z + wb.w * xb.w;
            p += __shfl_xor(p, 1);
            p += __shfl_xor(p, 2);
            p += __shfl_xor(p, 4);
            if (kp == 0) hbuf[s * 2048 + j] = fmaxf(p + b1, 0.f);
        }
    }
    grid_bar(bar + t * 4 + 0, NBLK);

    // FFN2 layer 0: one output dim per block
    {
        const int d = bid;
        const float4* w4 = (const float4*)(f2w + (size_t)d * 2048 + tid * 8);
        float4 w0 = w4[0], w1 = w4[1];
        for (int s = 0; s < S; s++) {
            const float4* h4 = (const float4*)(hbuf + s * 2048 + tid * 8);
            float4 h0 = h4[0], h1 = h4[1];
            float p = w0.x * h0.x + w0.y * h0.y + w0.z * h0.z + w0.w * h0.w
                    + w1.x * h1.x + w1.y * h1.y + w1.z * h1.z + w1.w * h1.w;
            #pragma unroll
            for (int o = 1; o < 64; o <<= 1) p += __shfl_xor(p, o);
            if ((tid & 63) == 0) sw[tid >> 6][s] = p;
        }
        __syncthreads();
        if (tid < S)
            y0[tid * 64 + d] = sw[0][tid] + sw[1][tid] + sw[2][tid] + sw[3][tid]
                             + f2b[d] + xps[tid * 64 + d];
    }
    grid_bar(bar + t * 4 + 1, NBLK);

    // LN2(y0) -> x (reused as layer-1 input), redundant per block
    for (int i = tid; i < S * 64; i += 256) y2[i] = y0[i];
    __syncthreads();
    if (tid < S) {
        const float* yr = y2 + tid * 64;
        float m = 0.f;
        for (int k = 0; k < 64; k++) m += yr[k];
        m *= (1.f / 64.f);
        float v = 0.f;
        for (int k = 0; k < 64; k++) { float df = yr[k] - m; v += df * df; }
        rm[tid] = m;
        rr[tid] = 1.f / sqrtf(v * (1.f / 64.f) + EPS_);
    }
    __syncthreads();
    for (int i = tid; i < S * 64; i += 256) {
        int s = i >> 6, d = i & 63;
        x[i] = (y2[i] - rm[s]) * rr[s] * l2w[d] + l2b[d];
    }
    __syncthreads();

    // QKV layer 1
    for (int i = tid; i < S * 192; i += 256) {
        int s = i / 192, j2 = i % 192;
        float acc = ipb1[j2];
        const float4* wr = (const float4*)(ipw1 + j2 * 64);
        const float4* xr = (const float4*)(x + s * 64);
        #pragma unroll
        for (int k = 0; k < 16; k++) {
            float4 w4 = wr[k], xv = xr[k];
            acc += w4.x * xv.x + w4.y * xv.y + w4.z * xv.z + w4.w * xv.w;
        }
        qkv[i] = acc;
    }
    __syncthreads();

    // attention layer 1: last query row only
    for (int i = tid; i < 4 * S; i += 256) {
        int h = i / S, ti = i % S;
        const float* qr = qkv + (S - 1) * 192 + h * 16;
        const float* kr = qkv + ti * 192 + 64 + h * 16;
        float acc = 0.f;
        #pragma unroll
        for (int k = 0; k < 16; k++) acc += qr[k] * kr[k];
        att[h * S + ti] = acc * 0.25f;
    }
    __syncthreads();
    if (tid < 4) {
        float* row = att + tid * S;
        float mx = row[0];
        for (int j2 = 1; j2 < S; j2++) mx = fmaxf(mx, row[j2]);
        float sm = 0.f;
        for (int j2 = 0; j2 < S; j2++) { float e = expf(row[j2] - mx); row[j2] = e; sm += e; }
        float inv = 1.f / sm;
        for (int j2 = 0; j2 < S; j2++) row[j2] *= inv;
    }
    __syncthreads();
    if (tid < 64) {
        int h = tid >> 4, dh = tid & 15;
        const float* ar = att + h * S;
        float acc = 0.f;
        for (int ti = 0; ti < S; ti++) acc += ar[ti] * qkv[ti * 192 + 128 + h * 16 + dh];
        ol[tid] = acc;
    }
    __syncthreads();
    if (tid < 64) {
        float acc = ob1[tid] + x[(S - 1) * 64 + tid];
        const float* wr = ow1 + tid * 64;
        for (int k = 0; k < 64; k++) acc += ol[k] * wr[k];
        y2l[tid] = acc;
    }
    __syncthreads();
    if (tid < 64) {
        float v = y2l[tid];
        float m = v;
        #pragma unroll
        for (int o = 1; o < 64; o <<= 1) m += __shfl_xor(m, o);
        m *= (1.f / 64.f);
        float df = v - m;
        float var = df * df;
        #pragma unroll
        for (int o = 1; o < 64; o <<= 1) var += __shfl_xor(var, o);
        float r = 1.f / sqrtf(var * (1.f / 64.f) + EPS_);
        xpl[tid] = df * r * l1w1[tid] + l1b1[tid];
    }
    __syncthreads();

    // FFN1 layer 1 (last row only)
    {
        const float4* wr = (const float4*)(f1w1 + (size_t)j * 64);
        float4 wa = wr[kp * 2], wb = wr[kp * 2 + 1];
        const float4* xr = (const float4*)xpl;
        float4 xa = xr[kp * 2], xb = xr[kp * 2 + 1];
        float p = wa.x * xa.x + wa.y * xa.y + wa.z * xa.z + wa.w * xa.w
                + wb.x * xb.x + wb.y * xb.y + wb.z * xb.z + wb.w * xb.w;
        p += __shfl_xor(p, 1);
        p += __shfl_xor(p, 2);
        p += __shfl_xor(p, 4);
        if (kp == 0) hbuf2[j] = fmaxf(p + f1b1[j], 0.f);
    }
    grid_bar(bar + t * 4 + 2, NBLK);

    // FFN2 layer 1 (last row) -> y_last
    {
        const int d = bid;
        const float4* w4 = (const float4*)(f2w1 + (size_t)d * 2048 + tid * 8);
        const float4* h4 = (const float4*)(hbuf2 + tid * 8);
        float4 w0 = w4[0], w1 = w4[1], h0 = h4[0], h1 = h4[1];
        float p = w0.x * h0.x + w0.y * h0.y + w0.z * h0.z + w0.w * h0.w
                + w1.x * h1.x + w1.y * h1.y + w1.z * h1.z + w1.w * h1.w;
        #pragma unroll
        for (int o = 1; o < 64; o <<= 1) p += __shfl_xor(p, o);
        if ((tid & 63) == 0) sw[tid >> 6][0] = p;
        __syncthreads();
        if (tid == 0) y_last[d] = sw[0][0] + sw[1][0] + sw[2][0] + sw[3][0] + f2b1[d] + xpl[d];
    }
}

// ---------------------------------------------------------------------------
// Step-0 scan: exact fp32 argmax approx + fused fp8 quantization of item_emb.
// Per-WAVE contiguous chunks of CH rows; cand[g] = chunk best. 2048 blocks.
// ---------------------------------------------------------------------------
__global__ __launch_bounds__(256) void scan0_kernel(
    const float* __restrict__ item_emb, const float* __restrict__ y_last,
    const float* __restrict__ lnw, const float* __restrict__ lnb,
    u64* __restrict__ cand, float* __restrict__ xl_all, u32* __restrict__ emb8)
{
    const int tid = threadIdx.x;
    __shared__ float xl[64];
    if (tid < 64) {
        float v = y_last[tid];
        float m = v;
        #pragma unroll
        for (int o = 1; o < 64; o <<= 1) m += __shfl_xor(m, o);
        m *= (1.f / 64.f);
        float df = v - m;
        float var = df * df;
        #pragma unroll
        for (int o = 1; o < 64; o <<= 1) var += __shfl_xor(var, o);
        float r = 1.f / sqrtf(var * (1.f / 64.f) + EPS_);
        float v_ = df * r * lnw[tid] + lnb[tid];
        xl[tid] = v_;
        if (blockIdx.x == 0) xl_all[tid] = v_;
    }
    __syncthreads();

    const int lane = tid & 63, wid = tid >> 6;
    const int g = blockIdx.x * 4 + wid;
    const int l16 = lane & 15, rl = lane >> 4;   // 4 rows per iter
    float4 q = ((const float4*)xl)[l16];
    const int r0 = g * CH;
    u64 lb = 0ull;
    for (int it = 0; it < 31; it++) {
        int loc = it * 4 + rl;
        int row = r0 + loc;
        if (loc < CH && row < V_) {
            float4 e = ((const float4*)(item_emb + (size_t)row * 64))[l16];
            u32 pk8 = (u32)__builtin_amdgcn_cvt_pk_fp8_f32(e.x * FP8_SCALE, e.y * FP8_SCALE, 0, false);
            pk8 = (u32)__builtin_amdgcn_cvt_pk_fp8_f32(e.z * FP8_SCALE, e.w * FP8_SCALE, (int)pk8, true);
            emb8[(size_t)row * 16 + l16] = pk8;
            float p = q.x * e.x + q.y * e.y + q.z * e.z + q.w * e.w;
            p += __shfl_xor(p, 1);
            p += __shfl_xor(p, 2);
            p += __shfl_xor(p, 4);
            p += __shfl_xor(p, 8);
            if (l16 == 0) { u64 pk = pack_best(p, row); if (pk > lb) lb = pk; }
        }
    }
    #pragma unroll
    for (int o = 1; o < 64; o <<= 1) { u64 xv = shfl_xor_u64(lb, o); if (xv > lb) lb = xv; }
    if (lane == 0) cand[g] = lb;
}

// ---------------------------------------------------------------------------
// Steps 1..9 argmax scan over the fp8 copy (64 MB). Same chunk mapping.
// ---------------------------------------------------------------------------
__global__ __launch_bounds__(256) void scan_fp8_kernel(
    const u32* __restrict__ emb8, const float* __restrict__ y_last,
    const float* __restrict__ lnw, const float* __restrict__ lnb,
    u64* __restrict__ cand, float* __restrict__ xl_all, int t)
{
    const int tid = threadIdx.x;
    __shared__ float xls[64];
    if (tid < 64) {
        float v = y_last[tid];
        float m = v;
        #pragma unroll
        for (int o = 1; o < 64; o <<= 1) m += __shfl_xor(m, o);
        m *= (1.f / 64.f);
        float df = v - m;
        float var = df * df;
        #pragma unroll
        for (int o = 1; o < 64; o <<= 1) var += __shfl_xor(var, o);
        float r = 1.f / sqrtf(var * (1.f / 64.f) + EPS_);
        float v_ = df * r * lnw[tid] + lnb[tid];
        if (blockIdx.x == 0) xl_all[t * 64 + tid] = v_;
        xls[tid] = v_ * FP8_INV;
    }
    __syncthreads();

    const int lane = tid & 63, wid = tid >> 6;
    const int g = blockIdx.x * 4 + wid;
    const int l4 = lane & 3, rl = lane >> 2;     // 16 rows per iter
    float q[16];
    #pragma unroll
    for (int i = 0; i < 16; i++) q[i] = xls[l4 * 16 + i];
    const int r0 = g * CH;
    u64 lb = 0ull;
    for (int it = 0; it < 8; it++) {
        int loc = it * 16 + rl;
        int row = r0 + loc;
        if (loc < CH && row < V_) {
            uint4 u = ((const uint4*)emb8)[(size_t)row * 4 + l4];
            float p;
            FP8_DOT16(u, q, p);
            p += __shfl_xor(p, 1);
            p += __shfl_xor(p, 2);
            if (l4 == 0) { u64 pk = pack_best(p, row); if (pk > lb) lb = pk; }
        }
    }
    #pragma unroll
    for (int o = 1; o < 64; o <<= 1) { u64 xv = shfl_xor_u64(lb, o); if (xv > lb) lb = xv; }
    if (lane == 0) cand[g] = lb;
}

// ---------------------------------------------------------------------------
// Final argmax resolve (step 9's token).
// ---------------------------------------------------------------------------
__global__ __launch_bounds__(256) void finalize_kernel(
    const u64* __restrict__ cand, const u32* __restrict__ emb8,
    const float* __restrict__ item_emb, const float* __restrict__ y_last,
    const float* __restrict__ lnw, const float* __restrict__ lnb,
    float* __restrict__ gen_out)
{
    __shared__ float xl[64];
    __shared__ int list[128], qg[64], cnt, qcnt;
    __shared__ u64 wm[4], best;
    int r = resolve_argmax(cand, emb8, item_emb, y_last, lnw, lnb,
                           xl, list, qg, wm, &cnt, &qcnt, &best);
    if (threadIdx.x == 0) gen_out[STEPS_ - 1] = (float)r;
}

// ---------------------------------------------------------------------------
// Batched exact logits: one fp32 pass over item_emb computes all 10 planes.
// 4 lanes/row (16 dims each); all 10 q-vectors in registers (160 VGPR);
// reduction = xor1+xor2 only (DPP quad-perm, no ds_swizzle, no LDS).
// Wave covers 16 contiguous rows = dense 4 KB per iteration.
// ---------------------------------------------------------------------------
__global__ __launch_bounds__(256) void logits_all_kernel(
    const float* __restrict__ item_emb, const float* __restrict__ xl_all,
    float* __restrict__ out)
{
    const int tid = threadIdx.x;
    const int lane = tid & 63, wv = tid >> 6;
    const int l4 = lane & 3, qd = lane >> 2;

    float4 qv[10][4];
    #pragma unroll
    for (int p = 0; p < 10; p++) {
        #pragma unroll
        for (int c = 0; c < 4; c++)
            qv[p][c] = *(const float4*)(xl_all + p * 64 + l4 * 16 + c * 4);
    }

    const int row_in_blk = wv * 16 + qd;            // 0..63
    for (int tile = blockIdx.x; tile < V_ / 64; tile += gridDim.x) {
        const int row = tile * 64 + row_in_blk;
        const float4* er = (const float4*)(item_emb + (size_t)row * 64 + l4 * 16);
        float4 e0 = er[0], e1 = er[1], e2 = er[2], e3 = er[3];
        float acc[10];
        #pragma unroll
        for (int p = 0; p < 10; p++) {
            float s = qv[p][0].x*e0.x + qv[p][0].y*e0.y + qv[p][0].z*e0.z + qv[p][0].w*e0.w
                    + qv[p][1].x*e1.x + qv[p][1].y*e1.y + qv[p][1].z*e1.z + qv[p][1].w*e1.w
                    + qv[p][2].x*e2.x + qv[p][2].y*e2.y + qv[p][2].z*e2.z + qv[p][2].w*e2.w
                    + qv[p][3].x*e3.x + qv[p][3].y*e3.y + qv[p][3].z*e3.z + qv[p][3].w*e3.w;
            s += __shfl_xor(s, 1);
            s += __shfl_xor(s, 2);
            acc[p] = s;
        }
        if (l4 == 0) {
            #pragma unroll
            for (int p = 0; p < 10; p++)
                out[(size_t)p * V_ + row] = acc[p];
        }
    }
}

extern "C" void kernel_launch(void* const* d_in, const int* in_sizes, int n_in,
                              void* d_out, int out_size, void* d_ws, size_t ws_size,
                              hipStream_t stream) {
    const float* ht       = (const float*)d_in[0];
    const float* item_emb = (const float*)d_in[1];
    const float* pos_emb  = (const float*)d_in[2];
    const float* ipw      = (const float*)d_in[3];
    const float* ipb      = (const float*)d_in[4];
    const float* ow       = (const float*)d_in[5];
    const float* ob       = (const float*)d_in[6];
    const float* l1w      = (const float*)d_in[7];
    const float* l1b      = (const float*)d_in[8];
    const float* l2w      = (const float*)d_in[9];
    const float* l2b      = (const float*)d_in[10];
    const float* f1w      = (const float*)d_in[11];
    const float* f1b      = (const float*)d_in[12];
    const float* f2w      = (const float*)d_in[13];
    const float* f2b      = (const float*)d_in[14];

    float* out = (float*)d_out;
    char* ws = (char*)d_ws;
    int*   gen_idx = (int*)ws;                 // [0,64)
    float* y_last  = (float*)(ws + 64);        // 64 floats
    float* y0      = (float*)(ws + 512);       // 10x64
    float* hbuf2   = (float*)(ws + 3072);      // 2048
    float* xl_all  = (float*)(ws + 11264);     // 10x64
    u32*   bar     = (u32*)(ws + 14336);       // 64 counters
    float* hbuf    = (float*)(ws + 16384);     // 10x2048
    u64*   cand    = (u64*)(ws + 131072);      // 8192 x u64
    u32*   emb8    = (u32*)(ws + 262144);      // 64 MB fp8 copy
    float* gen_out = out + (size_t)STEPS_ * V_;

    hipMemsetAsync(bar, 0, 256, stream);       // single-use barrier counters

    for (int t = 0; t < STEPS_; t++) {
        step_kernel<<<NBLK, 256, 0, stream>>>(
            ht, item_emb, pos_emb, ipw, ipb, ow, ob, l1w, l1b, l2w, l2b,
            f1w, f1b, f2w, f2b, cand, emb8, y_last, gen_idx, gen_out,
            y0, hbuf, hbuf2, bar, t);
        if (t == 0)
            scan0_kernel<<<2048, 256, 0, stream>>>(
                item_emb, y_last, l2w + 64, l2b + 64, cand, xl_all, emb8);
        else
            scan_fp8_kernel<<<2048, 256, 0, stream>>>(
                emb8, y_last, l2w + 64, l2b + 64, cand, xl_all, t);
    }
    finalize_kernel<<<1, 256, 0, stream>>>(
        cand, emb8, item_emb, y_last, l2w + 64, l2b + 64, gen_out);
    logits_all_kernel<<<2048, 256, 0, stream>>>(item_emb, xl_all, out);
}